// Round 17
// baseline (113.695 us; speedup 1.0000x reference)
//
#include <hip/hip_runtime.h>
#include <hip/hip_fp16.h>

#define NPTS  8192
#define DDIM  384
#define HCAP  1024
#define NTHR  512
#define NSLOT 8
#define NC    52
#define NCELL (NC * NC)           // 2704
#define GY0   -5.2005f
#define GHINV 4.99750124937531f   // 1/0.2001

// ws layout (bytes):
//  csS       half2[NPTS*DDIM]  @ 0         12582912   (sorted-order cos/sin, row = 1536 B)
//  xyS       float2[NPTS]      @ 12582912     65536
//  perm      int[NPTS]         @ 12648448     32768
//  cellStart int[NCELL+1]      @ 12681216     12288

__device__ __forceinline__ int cell_of(float a, float b)
{
    int c1 = (int)floorf((a - GY0) * GHINV);
    int c2 = (int)floorf((b - GY0) * GHINV);
    c1 = min(NC - 1, max(0, c1));
    c2 = min(NC - 1, max(0, c2));
    return c1 * NC + c2;
}

__device__ __forceinline__ __half2 u2h(unsigned u)
{
    union { unsigned u; __half2 h; } v; v.u = u; return v.h;
}
__device__ __forceinline__ unsigned h2u(__half2 h)
{
    union { unsigned u; __half2 h; } v; v.h = h; return v.u;
}

// Fused setup: bin + exclusive-scan + scatter, one workgroup.
// Scan parallelized (shfl wave-scan + cross-wave) vs R14's serial loop.
__global__ __launch_bounds__(1024)
void setup_kernel(const float* __restrict__ pts, int* __restrict__ cellStart,
                  int* __restrict__ perm, float2* __restrict__ xyS)
{
    __shared__ int cnt[NCELL];
    __shared__ int wsum[16];
    const int t    = threadIdx.x;
    const int lane = t & 63, wid = t >> 6;

    for (int c = t; c < NCELL; c += 1024) cnt[c] = 0;
    __syncthreads();
    for (int n = t; n < NPTS; n += 1024)
        atomicAdd(&cnt[cell_of(pts[3 * n + 1], pts[3 * n + 2])], 1);
    __syncthreads();

    const int base = t * 3;                 // 1024*3 >= 2704
    int s = 0;
    for (int c = base; c < base + 3 && c < NCELL; ++c) s += cnt[c];

    // inclusive wave scan
    int v = s;
    #pragma unroll
    for (int off = 1; off < 64; off <<= 1) {
        int u = __shfl_up(v, off, 64);
        if (lane >= off) v += u;
    }
    if (lane == 63) wsum[wid] = v;
    __syncthreads();
    if (wid == 0 && lane < 16) {
        int x = wsum[lane];
        #pragma unroll
        for (int off = 1; off < 16; off <<= 1) {
            int u = __shfl_up(x, off, 64);
            if (lane >= off) x += u;
        }
        wsum[lane] = x;
    }
    __syncthreads();
    int acc = v - s + (wid ? wsum[wid - 1] : 0);   // exclusive prefix

    for (int c = base; c < base + 3 && c < NCELL; ++c) {
        int val = cnt[c];
        cellStart[c] = acc;
        cnt[c] = acc;                       // becomes scatter cursor
        acc += val;
    }
    if (t == 0) cellStart[NCELL] = NPTS;
    __syncthreads();

    for (int n = t; n < NPTS; n += 1024) {
        float a = pts[3 * n + 1];
        float b = pts[3 * n + 2];
        int pos = atomicAdd(&cnt[cell_of(a, b)], 1);
        perm[pos] = n;
        xyS[pos]  = make_float2(a, b);
    }
}

__global__ __launch_bounds__(DDIM)
void cs_kernel(const float* __restrict__ pts, const float* __restrict__ A,
               const int* __restrict__ perm, __half2* __restrict__ csS)
{
    const int r = blockIdx.x;
    const int t = threadIdx.x;
    const int n = perm[r];
    const float p0 = pts[3 * n + 0];
    const float p1 = pts[3 * n + 1];
    const float p2 = pts[3 * n + 2];
    const float pa = fmaf(p2, A[2 * DDIM + t],
                     fmaf(p1, A[DDIM + t], __fmul_rn(p0, A[t])));
    float s, c;
    sincosf(pa, &s, &c);
    csS[r * DDIM + t] = __floats2half2_rn(c, s);
}

__global__ __launch_bounds__(NTHR)
void row_kernel(const __half2* __restrict__ csS, const float2* __restrict__ xyS,
                const int* __restrict__ perm, const int* __restrict__ cellStart,
                float* __restrict__ out)
{
    __shared__ int   hits[HCAP];
    __shared__ int   hcnt;
    __shared__ uint2 partl[NSLOT][64][3];
    __shared__ float red[NSLOT];

    // balance-preserving XCD swizzle: 64 chunks of 128 sorted rows
    const int bid = blockIdx.x;
    const int xcd = bid & 7, q = bid >> 3;
    const int ch  = q >> 7, w = q & 127;
    const int r   = (((ch << 3) + xcd) << 7) + w;

    const int t  = threadIdx.x;
    const int ks = t >> 6;      // wave id 0..7  (wave-uniform)
    const int cg = t & 63;      // lane

    if (t == 0) hcnt = 0;
    __syncthreads();

    const float2 me  = xyS[r];
    const float  xi  = me.x;
    const float  yi  = me.y;
    const float  sqi = __fadd_rn(__fmul_rn(xi, xi), __fmul_rn(yi, yi));

    int c1 = (int)floorf((xi - GY0) * GHINV);
    int c2 = (int)floorf((yi - GY0) * GHINV);
    c1 = min(NC - 1, max(0, c1));
    c2 = min(NC - 1, max(0, c2));
    const int c1lo = max(0, c1 - 1), c1hi = min(NC - 1, c1 + 1);
    const int c2lo = max(0, c2 - 1), c2hi = min(NC - 1, c2 + 1);

    for (int cr = c1lo; cr <= c1hi; ++cr) {
        const int qlo = cellStart[cr * NC + c2lo];
        const int qhi = cellStart[cr * NC + c2hi + 1];
        for (int qq = qlo + t; qq < qhi; qq += NTHR) {
            const float2 pj  = xyS[qq];
            const float  sqj = __fadd_rn(__fmul_rn(pj.x, pj.x), __fmul_rn(pj.y, pj.y));
            const float  dot = fmaf(yi, pj.y, __fmul_rn(xi, pj.x));
            const float  d2  = __fsub_rn(__fadd_rn(sqi, sqj), __fmul_rn(2.0f, dot));
            if (d2 < 0.04f) {                       // exact fp32 J test (unchanged)
                int p = atomicAdd(&hcnt, 1);
                if (p < HCAP) hits[p] = qq;
            }
        }
    }
    __syncthreads();
    const int m = hcnt < HCAP ? hcnt : HCAP;

    // gather: slot ks takes rows k+ks (k step 8). CONTIGUOUS wave-loads:
    // lane cg loads 8B at row-offset cg*8 + {0,512,1024} -> each wave-load
    // spans 512 contiguous B = 8 cache lines (was 24 at stride-24). Thread
    // accumulates cols {2cg,2cg+1}, {128+2cg,...}, {256+2cg,...}.
    const char* base = (const char*)csS;
    const int   b0   = cg * 8;

    __half2 a0 = u2h(0), a1 = u2h(0), a2 = u2h(0),
            a3 = u2h(0), a4 = u2h(0), a5 = u2h(0);
    int k = 0;
    for (; k + 32 <= m; k += 32) {
        const int jA = __builtin_amdgcn_readfirstlane(hits[k + ks]);
        const int jB = __builtin_amdgcn_readfirstlane(hits[k + 8 + ks]);
        const int jC = __builtin_amdgcn_readfirstlane(hits[k + 16 + ks]);
        const int jD = __builtin_amdgcn_readfirstlane(hits[k + 24 + ks]);
        const char* rA = base + jA * 1536 + b0;
        const char* rB = base + jB * 1536 + b0;
        const char* rC = base + jC * 1536 + b0;
        const char* rD = base + jD * 1536 + b0;
        const uint2 wA0 = *(const uint2*)(rA);
        const uint2 wA1 = *(const uint2*)(rA + 512);
        const uint2 wA2 = *(const uint2*)(rA + 1024);
        const uint2 wB0 = *(const uint2*)(rB);
        const uint2 wB1 = *(const uint2*)(rB + 512);
        const uint2 wB2 = *(const uint2*)(rB + 1024);
        const uint2 wC0 = *(const uint2*)(rC);
        const uint2 wC1 = *(const uint2*)(rC + 512);
        const uint2 wC2 = *(const uint2*)(rC + 1024);
        const uint2 wD0 = *(const uint2*)(rD);
        const uint2 wD1 = *(const uint2*)(rD + 512);
        const uint2 wD2 = *(const uint2*)(rD + 1024);
        a0 = __hadd2(a0, u2h(wA0.x)); a1 = __hadd2(a1, u2h(wA0.y));
        a2 = __hadd2(a2, u2h(wA1.x)); a3 = __hadd2(a3, u2h(wA1.y));
        a4 = __hadd2(a4, u2h(wA2.x)); a5 = __hadd2(a5, u2h(wA2.y));
        a0 = __hadd2(a0, u2h(wB0.x)); a1 = __hadd2(a1, u2h(wB0.y));
        a2 = __hadd2(a2, u2h(wB1.x)); a3 = __hadd2(a3, u2h(wB1.y));
        a4 = __hadd2(a4, u2h(wB2.x)); a5 = __hadd2(a5, u2h(wB2.y));
        a0 = __hadd2(a0, u2h(wC0.x)); a1 = __hadd2(a1, u2h(wC0.y));
        a2 = __hadd2(a2, u2h(wC1.x)); a3 = __hadd2(a3, u2h(wC1.y));
        a4 = __hadd2(a4, u2h(wC2.x)); a5 = __hadd2(a5, u2h(wC2.y));
        a0 = __hadd2(a0, u2h(wD0.x)); a1 = __hadd2(a1, u2h(wD0.y));
        a2 = __hadd2(a2, u2h(wD1.x)); a3 = __hadd2(a3, u2h(wD1.y));
        a4 = __hadd2(a4, u2h(wD2.x)); a5 = __hadd2(a5, u2h(wD2.y));
    }
    for (; k + 16 <= m; k += 16) {
        const int jA = __builtin_amdgcn_readfirstlane(hits[k + ks]);
        const int jB = __builtin_amdgcn_readfirstlane(hits[k + 8 + ks]);
        const char* rA = base + jA * 1536 + b0;
        const char* rB = base + jB * 1536 + b0;
        const uint2 wA0 = *(const uint2*)(rA);
        const uint2 wA1 = *(const uint2*)(rA + 512);
        const uint2 wA2 = *(const uint2*)(rA + 1024);
        const uint2 wB0 = *(const uint2*)(rB);
        const uint2 wB1 = *(const uint2*)(rB + 512);
        const uint2 wB2 = *(const uint2*)(rB + 1024);
        a0 = __hadd2(a0, u2h(wA0.x)); a1 = __hadd2(a1, u2h(wA0.y));
        a2 = __hadd2(a2, u2h(wA1.x)); a3 = __hadd2(a3, u2h(wA1.y));
        a4 = __hadd2(a4, u2h(wA2.x)); a5 = __hadd2(a5, u2h(wA2.y));
        a0 = __hadd2(a0, u2h(wB0.x)); a1 = __hadd2(a1, u2h(wB0.y));
        a2 = __hadd2(a2, u2h(wB1.x)); a3 = __hadd2(a3, u2h(wB1.y));
        a4 = __hadd2(a4, u2h(wB2.x)); a5 = __hadd2(a5, u2h(wB2.y));
    }
    for (; k < m; k += NSLOT) {
        if (k + ks < m) {                            // wave-uniform
            const int j = __builtin_amdgcn_readfirstlane(hits[k + ks]);
            const char* rA = base + j * 1536 + b0;
            const uint2 wA0 = *(const uint2*)(rA);
            const uint2 wA1 = *(const uint2*)(rA + 512);
            const uint2 wA2 = *(const uint2*)(rA + 1024);
            a0 = __hadd2(a0, u2h(wA0.x)); a1 = __hadd2(a1, u2h(wA0.y));
            a2 = __hadd2(a2, u2h(wA1.x)); a3 = __hadd2(a3, u2h(wA1.y));
            a4 = __hadd2(a4, u2h(wA2.x)); a5 = __hadd2(a5, u2h(wA2.y));
        }
    }

    // partl[ks][cg][w] = cols {128w+2cg, 128w+2cg+1}
    partl[ks][cg][0] = make_uint2(h2u(a0), h2u(a1));
    partl[ks][cg][1] = make_uint2(h2u(a2), h2u(a3));
    partl[ks][cg][2] = make_uint2(h2u(a4), h2u(a5));
    __syncthreads();

    // fold 8 slots: thread t (< 384) owns column t.
    // col t: w = t/128, u = t%128, lane = u>>1, sel = u&1
    float re = 0.f, im = 0.f;
    if (t < DDIM) {
        const int wq = t >> 7, u = t & 127;
        const int ln = u >> 1, sel = u & 1;
        #pragma unroll
        for (int s = 0; s < NSLOT; ++s) {
            const uint2 ww = partl[s][ln][wq];
            const float2 f = __half22float2(u2h(sel ? ww.y : ww.x));
            re += f.x; im += f.y;
        }
    }

    // row norm (threads >= 384 contribute 0)
    float p = fmaf(re, re, im * im);
    #pragma unroll
    for (int off = 32; off > 0; off >>= 1) p += __shfl_down(p, off, 64);
    if ((t & 63) == 0) red[t >> 6] = p;
    __syncthreads();
    const float tot = ((red[0] + red[1]) + (red[2] + red[3]))
                    + ((red[4] + red[5]) + (red[6] + red[7]));
    const float scale = 19.59591794226543f / sqrtf(tot);   // sqrt(384)/nrm

    if (t < DDIM) {
        // rotation by conj(e^{i pa_i}) using the (L2-hot) table row itself
        const float2 ci = __half22float2(csS[r * DDIM + t]);
        const float  Gr = fmaf(re, ci.x, im * ci.y);
        out[perm[r] * DDIM + t] = Gr * scale;
    }
}

extern "C" void kernel_launch(void* const* d_in, const int* in_sizes, int n_in,
                              void* d_out, int out_size, void* d_ws, size_t ws_size,
                              hipStream_t stream)
{
    const float* pts = (const float*)d_in[0];
    const float* A   = (const float*)d_in[1];
    if (n_in >= 2 && in_sizes[0] == 3 * DDIM && in_sizes[1] == NPTS * 3) {
        pts = (const float*)d_in[1];
        A   = (const float*)d_in[0];
    }
    char* ws = (char*)d_ws;
    __half2* csS       = (__half2*)(ws + 0);
    float2*  xyS       = (float2*)(ws + 12582912);
    int*     perm      = (int*)(ws + 12648448);
    int*     cellStart = (int*)(ws + 12681216);
    float*   out       = (float*)d_out;

    setup_kernel<<<1, 1024, 0, stream>>>(pts, cellStart, perm, xyS);
    cs_kernel<<<NPTS, DDIM, 0, stream>>>(pts, A, perm, csS);
    row_kernel<<<NPTS, NTHR, 0, stream>>>(csS, xyS, perm, cellStart, out);
}

// Round 18
// 71.364 us; speedup vs baseline: 1.5932x; 1.5932x over previous
//
#include <hip/hip_runtime.h>
#include <hip/hip_fp16.h>

#define NPTS  8192
#define DDIM  384
#define ROWS  4
#define NBLK  (NPTS / ROWS)       // 2048
#define UCAP  1536
#define NTHR  512
#define NSLOT 8
#define NC    52
#define NCELL (NC * NC)           // 2704
#define GY0   -5.2005f
#define GHINV 4.99750124937531f   // 1/0.2001

// ws layout (bytes):
//  csS       half2[NPTS*DDIM]  @ 0         12582912   (sorted-order cos/sin, row = 1536 B)
//  xyS       float2[NPTS]      @ 12582912     65536
//  perm      int[NPTS]         @ 12648448     32768
//  cellStart int[NCELL+1]      @ 12681216     12288

__device__ __forceinline__ int cell_of(float a, float b)
{
    int c1 = (int)floorf((a - GY0) * GHINV);
    int c2 = (int)floorf((b - GY0) * GHINV);
    c1 = min(NC - 1, max(0, c1));
    c2 = min(NC - 1, max(0, c2));
    return c1 * NC + c2;
}

__device__ __forceinline__ __half2 u2h(unsigned u)
{
    union { unsigned u; __half2 h; } v; v.u = u; return v.h;
}
__device__ __forceinline__ unsigned h2u(__half2 h)
{
    union { unsigned u; __half2 h; } v; v.h = h; return v.u;
}

// Fused setup: bin + parallel exclusive-scan + scatter (proven R16).
__global__ __launch_bounds__(1024)
void setup_kernel(const float* __restrict__ pts, int* __restrict__ cellStart,
                  int* __restrict__ perm, float2* __restrict__ xyS)
{
    __shared__ int cnt[NCELL];
    __shared__ int wsum[16];
    const int t    = threadIdx.x;
    const int lane = t & 63, wid = t >> 6;

    for (int c = t; c < NCELL; c += 1024) cnt[c] = 0;
    __syncthreads();
    for (int n = t; n < NPTS; n += 1024)
        atomicAdd(&cnt[cell_of(pts[3 * n + 1], pts[3 * n + 2])], 1);
    __syncthreads();

    const int base = t * 3;                 // 1024*3 >= 2704
    int s = 0;
    for (int c = base; c < base + 3 && c < NCELL; ++c) s += cnt[c];

    int v = s;
    #pragma unroll
    for (int off = 1; off < 64; off <<= 1) {
        int u = __shfl_up(v, off, 64);
        if (lane >= off) v += u;
    }
    if (lane == 63) wsum[wid] = v;
    __syncthreads();
    if (wid == 0 && lane < 16) {
        int x = wsum[lane];
        #pragma unroll
        for (int off = 1; off < 16; off <<= 1) {
            int u = __shfl_up(x, off, 64);
            if (lane >= off) x += u;
        }
        wsum[lane] = x;
    }
    __syncthreads();
    int acc = v - s + (wid ? wsum[wid - 1] : 0);   // exclusive prefix

    for (int c = base; c < base + 3 && c < NCELL; ++c) {
        int val = cnt[c];
        cellStart[c] = acc;
        cnt[c] = acc;                       // becomes scatter cursor
        acc += val;
    }
    if (t == 0) cellStart[NCELL] = NPTS;
    __syncthreads();

    for (int n = t; n < NPTS; n += 1024) {
        float a = pts[3 * n + 1];
        float b = pts[3 * n + 2];
        int pos = atomicAdd(&cnt[cell_of(a, b)], 1);
        perm[pos] = n;
        xyS[pos]  = make_float2(a, b);
    }
}

__global__ __launch_bounds__(DDIM)
void cs_kernel(const float* __restrict__ pts, const float* __restrict__ A,
               const int* __restrict__ perm, __half2* __restrict__ csS)
{
    const int r = blockIdx.x;
    const int t = threadIdx.x;
    const int n = perm[r];
    const float p0 = pts[3 * n + 0];
    const float p1 = pts[3 * n + 1];
    const float p2 = pts[3 * n + 2];
    const float pa = fmaf(p2, A[2 * DDIM + t],
                     fmaf(p1, A[DDIM + t], __fmul_rn(p0, A[t])));
    float s, c;
    sincosf(pa, &s, &c);
    csS[r * DDIM + t] = __floats2half2_rn(c, s);
}

__global__ __launch_bounds__(NTHR)
void row_kernel(const __half2* __restrict__ csS, const float2* __restrict__ xyS,
                const int* __restrict__ perm, const int* __restrict__ cellStart,
                float* __restrict__ out)
{
    __shared__ int   ulist[UCAP];
    __shared__ int   ucnt;
    __shared__ uint2 partl[NSLOT][64][3];
    __shared__ float red[NSLOT];

    // balance-preserving XCD swizzle: 64 chunks of 32 blocks (128 sorted rows)
    const int bid = blockIdx.x;
    const int xcd = bid & 7, q = bid >> 3;
    const int ch  = q >> 5, w = q & 31;
    const int blk = (((ch << 3) + xcd) << 5) + w;   // bijective on [0,2048)
    const int r0  = blk * ROWS;

    const int t  = threadIdx.x;
    const int ks = t >> 6;      // wave id 0..7  (wave-uniform)
    const int cg = t & 63;      // lane: owns cols 6cg..6cg+5

    if (t == 0) ucnt = 0;
    __syncthreads();

    float rx[ROWS], ry[ROWS], rs[ROWS];
    #pragma unroll
    for (int rr = 0; rr < ROWS; ++rr) {
        const float2 p = xyS[r0 + rr];
        rx[rr] = p.x; ry[rr] = p.y;
        rs[rr] = __fadd_rn(__fmul_rn(p.x, p.x), __fmul_rn(p.y, p.y));
    }

    // dilated cell window over the 4 rows
    int c1lo = NC - 1, c1hi = 0, c2lo = NC - 1, c2hi = 0;
    #pragma unroll
    for (int rr = 0; rr < ROWS; ++rr) {
        int c1 = (int)floorf((rx[rr] - GY0) * GHINV);
        int c2 = (int)floorf((ry[rr] - GY0) * GHINV);
        c1 = min(NC - 1, max(0, c1)); c2 = min(NC - 1, max(0, c2));
        c1lo = min(c1lo, c1); c1hi = max(c1hi, c1);
        c2lo = min(c2lo, c2); c2hi = max(c2hi, c2);
    }
    c1lo = max(0, c1lo - 1); c1hi = min(NC - 1, c1hi + 1);
    c2lo = max(0, c2lo - 1); c2hi = min(NC - 1, c2hi + 1);

    // scan: exact fp32 J test (bit-identical) vs the 4 rows -> 4-bit mask;
    // union entry packed as (mask<<13)|idx
    for (int cr = c1lo; cr <= c1hi; ++cr) {
        const int qlo = cellStart[cr * NC + c2lo];
        const int qhi = cellStart[cr * NC + c2hi + 1];
        for (int qq = qlo + t; qq < qhi; qq += NTHR) {
            const float2 pj  = xyS[qq];
            const float  sqj = __fadd_rn(__fmul_rn(pj.x, pj.x), __fmul_rn(pj.y, pj.y));
            int bits = 0;
            #pragma unroll
            for (int rr = 0; rr < ROWS; ++rr) {
                const float dot = fmaf(ry[rr], pj.y, __fmul_rn(rx[rr], pj.x));
                const float d2  = __fsub_rn(__fadd_rn(rs[rr], sqj), __fmul_rn(2.0f, dot));
                if (d2 < 0.04f) bits |= (1 << rr);
            }
            if (bits) {
                int p = atomicAdd(&ucnt, 1);
                if (p < UCAP) ulist[p] = qq | (bits << 13);
            }
        }
    }
    __syncthreads();
    const int U = ucnt < UCAP ? ucnt : UCAP;

    // gather: slot ks takes union entries k+ks (k step 8); per entry 3 loads
    // (stride-24 pattern, proven fastest) + mask-predicated (SGPR-uniform
    // branch) pk_adds into 4 per-row accumulator sets
    const char* base = (const char*)csS;
    const int   b0   = cg * 24;

    __half2 acc[ROWS][6];
    #pragma unroll
    for (int rr = 0; rr < ROWS; ++rr)
        #pragma unroll
        for (int c = 0; c < 6; ++c) acc[rr][c] = u2h(0);

    int k = 0;
    for (; k + 16 <= U; k += 16) {
        const int pkA = __builtin_amdgcn_readfirstlane(ulist[k + ks]);
        const int pkB = __builtin_amdgcn_readfirstlane(ulist[k + 8 + ks]);
        const int jA = pkA & 0x1FFF, mA = pkA >> 13;
        const int jB = pkB & 0x1FFF, mB = pkB >> 13;
        const char* rA = base + jA * 1536 + b0;
        const char* rB = base + jB * 1536 + b0;
        const uint2 wA0 = *(const uint2*)(rA);
        const uint2 wA1 = *(const uint2*)(rA + 8);
        const uint2 wA2 = *(const uint2*)(rA + 16);
        const uint2 wB0 = *(const uint2*)(rB);
        const uint2 wB1 = *(const uint2*)(rB + 8);
        const uint2 wB2 = *(const uint2*)(rB + 16);
        #pragma unroll
        for (int rr = 0; rr < ROWS; ++rr) {
            if (mA & (1 << rr)) {
                acc[rr][0] = __hadd2(acc[rr][0], u2h(wA0.x));
                acc[rr][1] = __hadd2(acc[rr][1], u2h(wA0.y));
                acc[rr][2] = __hadd2(acc[rr][2], u2h(wA1.x));
                acc[rr][3] = __hadd2(acc[rr][3], u2h(wA1.y));
                acc[rr][4] = __hadd2(acc[rr][4], u2h(wA2.x));
                acc[rr][5] = __hadd2(acc[rr][5], u2h(wA2.y));
            }
        }
        #pragma unroll
        for (int rr = 0; rr < ROWS; ++rr) {
            if (mB & (1 << rr)) {
                acc[rr][0] = __hadd2(acc[rr][0], u2h(wB0.x));
                acc[rr][1] = __hadd2(acc[rr][1], u2h(wB0.y));
                acc[rr][2] = __hadd2(acc[rr][2], u2h(wB1.x));
                acc[rr][3] = __hadd2(acc[rr][3], u2h(wB1.y));
                acc[rr][4] = __hadd2(acc[rr][4], u2h(wB2.x));
                acc[rr][5] = __hadd2(acc[rr][5], u2h(wB2.y));
            }
        }
    }
    for (; k < U; k += NSLOT) {
        if (k + ks < U) {                            // wave-uniform
            const int pkA = __builtin_amdgcn_readfirstlane(ulist[k + ks]);
            const int jA = pkA & 0x1FFF, mA = pkA >> 13;
            const char* rA = base + jA * 1536 + b0;
            const uint2 wA0 = *(const uint2*)(rA);
            const uint2 wA1 = *(const uint2*)(rA + 8);
            const uint2 wA2 = *(const uint2*)(rA + 16);
            #pragma unroll
            for (int rr = 0; rr < ROWS; ++rr) {
                if (mA & (1 << rr)) {
                    acc[rr][0] = __hadd2(acc[rr][0], u2h(wA0.x));
                    acc[rr][1] = __hadd2(acc[rr][1], u2h(wA0.y));
                    acc[rr][2] = __hadd2(acc[rr][2], u2h(wA1.x));
                    acc[rr][3] = __hadd2(acc[rr][3], u2h(wA1.y));
                    acc[rr][4] = __hadd2(acc[rr][4], u2h(wA2.x));
                    acc[rr][5] = __hadd2(acc[rr][5], u2h(wA2.y));
                }
            }
        }
    }

    // fold + norm + write, one row at a time through the shared partl buffer
    for (int rr = 0; rr < ROWS; ++rr) {
        partl[ks][cg][0] = make_uint2(h2u(acc[rr][0]), h2u(acc[rr][1]));
        partl[ks][cg][1] = make_uint2(h2u(acc[rr][2]), h2u(acc[rr][3]));
        partl[ks][cg][2] = make_uint2(h2u(acc[rr][4]), h2u(acc[rr][5]));
        __syncthreads();

        float re = 0.f, im = 0.f;
        if (t < DDIM) {
            const int sc = t / 6, comp = t % 6;
            #pragma unroll
            for (int s = 0; s < NSLOT; ++s) {
                const uint2 ww = partl[s][sc][comp >> 1];
                const float2 f = __half22float2(u2h((comp & 1) ? ww.y : ww.x));
                re += f.x; im += f.y;
            }
        }

        float p = fmaf(re, re, im * im);
        #pragma unroll
        for (int off = 32; off > 0; off >>= 1) p += __shfl_down(p, off, 64);
        if ((t & 63) == 0) red[t >> 6] = p;
        __syncthreads();
        const float tot = ((red[0] + red[1]) + (red[2] + red[3]))
                        + ((red[4] + red[5]) + (red[6] + red[7]));
        const float scale = 19.59591794226543f / sqrtf(tot);   // sqrt(384)/nrm

        if (t < DDIM) {
            const float2 ci = __half22float2(csS[(r0 + rr) * DDIM + t]);
            const float  Gr = fmaf(re, ci.x, im * ci.y);
            out[perm[r0 + rr] * DDIM + t] = Gr * scale;
        }
        __syncthreads();   // protect partl/red before next row's overwrite
    }
}

extern "C" void kernel_launch(void* const* d_in, const int* in_sizes, int n_in,
                              void* d_out, int out_size, void* d_ws, size_t ws_size,
                              hipStream_t stream)
{
    const float* pts = (const float*)d_in[0];
    const float* A   = (const float*)d_in[1];
    if (n_in >= 2 && in_sizes[0] == 3 * DDIM && in_sizes[1] == NPTS * 3) {
        pts = (const float*)d_in[1];
        A   = (const float*)d_in[0];
    }
    char* ws = (char*)d_ws;
    __half2* csS       = (__half2*)(ws + 0);
    float2*  xyS       = (float2*)(ws + 12582912);
    int*     perm      = (int*)(ws + 12648448);
    int*     cellStart = (int*)(ws + 12681216);
    float*   out       = (float*)d_out;

    setup_kernel<<<1, 1024, 0, stream>>>(pts, cellStart, perm, xyS);
    cs_kernel<<<NPTS, DDIM, 0, stream>>>(pts, A, perm, csS);
    row_kernel<<<NBLK, NTHR, 0, stream>>>(csS, xyS, perm, cellStart, out);
}

// Round 19
// 71.353 us; speedup vs baseline: 1.5934x; 1.0001x over previous
//
#include <hip/hip_runtime.h>
#include <hip/hip_fp16.h>

#define NPTS  8192
#define DDIM  384
#define ROWS  8
#define NBLK  (NPTS / ROWS)       // 1024
#define UCAP  1536
#define NTHR  512
#define NSLOT 8
#define NC    52
#define NCELL (NC * NC)           // 2704
#define GY0   -5.2005f
#define GHINV 4.99750124937531f   // 1/0.2001

// ws layout (bytes):
//  csS       half2[NPTS*DDIM]  @ 0         12582912   (sorted-order cos/sin, row = 1536 B)
//  xyS       float2[NPTS]      @ 12582912     65536
//  perm      int[NPTS]         @ 12648448     32768
//  cellStart int[NCELL+1]      @ 12681216     12288

__device__ __forceinline__ int cell_of(float a, float b)
{
    int c1 = (int)floorf((a - GY0) * GHINV);
    int c2 = (int)floorf((b - GY0) * GHINV);
    c1 = min(NC - 1, max(0, c1));
    c2 = min(NC - 1, max(0, c2));
    return c1 * NC + c2;
}

__device__ __forceinline__ __half2 u2h(unsigned u)
{
    union { unsigned u; __half2 h; } v; v.u = u; return v.h;
}
__device__ __forceinline__ unsigned h2u(__half2 h)
{
    union { unsigned u; __half2 h; } v; v.h = h; return v.u;
}

// Fused setup: bin + parallel exclusive-scan + scatter (proven R16-R18).
__global__ __launch_bounds__(1024)
void setup_kernel(const float* __restrict__ pts, int* __restrict__ cellStart,
                  int* __restrict__ perm, float2* __restrict__ xyS)
{
    __shared__ int cnt[NCELL];
    __shared__ int wsum[16];
    const int t    = threadIdx.x;
    const int lane = t & 63, wid = t >> 6;

    for (int c = t; c < NCELL; c += 1024) cnt[c] = 0;
    __syncthreads();
    for (int n = t; n < NPTS; n += 1024)
        atomicAdd(&cnt[cell_of(pts[3 * n + 1], pts[3 * n + 2])], 1);
    __syncthreads();

    const int base = t * 3;                 // 1024*3 >= 2704
    int s = 0;
    for (int c = base; c < base + 3 && c < NCELL; ++c) s += cnt[c];

    int v = s;
    #pragma unroll
    for (int off = 1; off < 64; off <<= 1) {
        int u = __shfl_up(v, off, 64);
        if (lane >= off) v += u;
    }
    if (lane == 63) wsum[wid] = v;
    __syncthreads();
    if (wid == 0 && lane < 16) {
        int x = wsum[lane];
        #pragma unroll
        for (int off = 1; off < 16; off <<= 1) {
            int u = __shfl_up(x, off, 64);
            if (lane >= off) x += u;
        }
        wsum[lane] = x;
    }
    __syncthreads();
    int acc = v - s + (wid ? wsum[wid - 1] : 0);   // exclusive prefix

    for (int c = base; c < base + 3 && c < NCELL; ++c) {
        int val = cnt[c];
        cellStart[c] = acc;
        cnt[c] = acc;                       // becomes scatter cursor
        acc += val;
    }
    if (t == 0) cellStart[NCELL] = NPTS;
    __syncthreads();

    for (int n = t; n < NPTS; n += 1024) {
        float a = pts[3 * n + 1];
        float b = pts[3 * n + 2];
        int pos = atomicAdd(&cnt[cell_of(a, b)], 1);
        perm[pos] = n;
        xyS[pos]  = make_float2(a, b);
    }
}

__global__ __launch_bounds__(DDIM)
void cs_kernel(const float* __restrict__ pts, const float* __restrict__ A,
               const int* __restrict__ perm, __half2* __restrict__ csS)
{
    const int r = blockIdx.x;
    const int t = threadIdx.x;
    const int n = perm[r];
    const float p0 = pts[3 * n + 0];
    const float p1 = pts[3 * n + 1];
    const float p2 = pts[3 * n + 2];
    const float pa = fmaf(p2, A[2 * DDIM + t],
                     fmaf(p1, A[DDIM + t], __fmul_rn(p0, A[t])));
    // fast HW sin/cos: error ~1e-6 << fp16 table ulp (5e-4); J-exactness
    // is untouched (distance test only).
    const float s = __sinf(pa);
    const float c = __cosf(pa);
    csS[r * DDIM + t] = __floats2half2_rn(c, s);
}

__global__ __launch_bounds__(NTHR)
void row_kernel(const __half2* __restrict__ csS, const float2* __restrict__ xyS,
                const int* __restrict__ perm, const int* __restrict__ cellStart,
                float* __restrict__ out)
{
    __shared__ int   ulist[UCAP];
    __shared__ int   ucnt;
    __shared__ uint2 partl[NSLOT][64][3];
    __shared__ float red[NSLOT];

    // balance-preserving XCD swizzle: 64 chunks of 16 blocks (128 sorted rows)
    const int bid = blockIdx.x;
    const int xcd = bid & 7, q = bid >> 3;
    const int ch  = q >> 4, w = q & 15;
    const int blk = (((ch << 3) + xcd) << 4) + w;   // bijective on [0,1024)
    const int r0  = blk * ROWS;

    const int t  = threadIdx.x;
    const int ks = t >> 6;      // wave id 0..7  (wave-uniform)
    const int cg = t & 63;      // lane: owns cols 6cg..6cg+5

    if (t == 0) ucnt = 0;
    __syncthreads();

    float rx[ROWS], ry[ROWS], rs[ROWS];
    #pragma unroll
    for (int rr = 0; rr < ROWS; ++rr) {
        const float2 p = xyS[r0 + rr];
        rx[rr] = p.x; ry[rr] = p.y;
        rs[rr] = __fadd_rn(__fmul_rn(p.x, p.x), __fmul_rn(p.y, p.y));
    }

    // dilated cell window over the 8 rows
    int c1lo = NC - 1, c1hi = 0, c2lo = NC - 1, c2hi = 0;
    #pragma unroll
    for (int rr = 0; rr < ROWS; ++rr) {
        int c1 = (int)floorf((rx[rr] - GY0) * GHINV);
        int c2 = (int)floorf((ry[rr] - GY0) * GHINV);
        c1 = min(NC - 1, max(0, c1)); c2 = min(NC - 1, max(0, c2));
        c1lo = min(c1lo, c1); c1hi = max(c1hi, c1);
        c2lo = min(c2lo, c2); c2hi = max(c2hi, c2);
    }
    c1lo = max(0, c1lo - 1); c1hi = min(NC - 1, c1hi + 1);
    c2lo = max(0, c2lo - 1); c2hi = min(NC - 1, c2hi + 1);

    // scan: exact fp32 J test (bit-identical) vs the 8 rows -> 8-bit mask;
    // union entry packed as (mask<<13)|idx
    for (int cr = c1lo; cr <= c1hi; ++cr) {
        const int qlo = cellStart[cr * NC + c2lo];
        const int qhi = cellStart[cr * NC + c2hi + 1];
        for (int qq = qlo + t; qq < qhi; qq += NTHR) {
            const float2 pj  = xyS[qq];
            const float  sqj = __fadd_rn(__fmul_rn(pj.x, pj.x), __fmul_rn(pj.y, pj.y));
            int bits = 0;
            #pragma unroll
            for (int rr = 0; rr < ROWS; ++rr) {
                const float dot = fmaf(ry[rr], pj.y, __fmul_rn(rx[rr], pj.x));
                const float d2  = __fsub_rn(__fadd_rn(rs[rr], sqj), __fmul_rn(2.0f, dot));
                if (d2 < 0.04f) bits |= (1 << rr);
            }
            if (bits) {
                int p = atomicAdd(&ucnt, 1);
                if (p < UCAP) ulist[p] = qq | (bits << 13);
            }
        }
    }
    __syncthreads();
    const int U = ucnt < UCAP ? ucnt : UCAP;

    // gather: slot ks takes union entries k+ks (k step 8); per entry 3 loads
    // (stride-24, proven fastest) + wave-uniform mask branches into 8 per-row
    // fp16 accumulator sets
    const char* base = (const char*)csS;
    const int   b0   = cg * 24;

    __half2 acc[ROWS][6];
    #pragma unroll
    for (int rr = 0; rr < ROWS; ++rr)
        #pragma unroll
        for (int c = 0; c < 6; ++c) acc[rr][c] = u2h(0);

    int k = 0;
    for (; k + 16 <= U; k += 16) {
        const int pkA = __builtin_amdgcn_readfirstlane(ulist[k + ks]);
        const int pkB = __builtin_amdgcn_readfirstlane(ulist[k + 8 + ks]);
        const int jA = pkA & 0x1FFF, mA = pkA >> 13;
        const int jB = pkB & 0x1FFF, mB = pkB >> 13;
        const char* rA = base + jA * 1536 + b0;
        const char* rB = base + jB * 1536 + b0;
        const uint2 wA0 = *(const uint2*)(rA);
        const uint2 wA1 = *(const uint2*)(rA + 8);
        const uint2 wA2 = *(const uint2*)(rA + 16);
        const uint2 wB0 = *(const uint2*)(rB);
        const uint2 wB1 = *(const uint2*)(rB + 8);
        const uint2 wB2 = *(const uint2*)(rB + 16);
        #pragma unroll
        for (int rr = 0; rr < ROWS; ++rr) {
            if (mA & (1 << rr)) {
                acc[rr][0] = __hadd2(acc[rr][0], u2h(wA0.x));
                acc[rr][1] = __hadd2(acc[rr][1], u2h(wA0.y));
                acc[rr][2] = __hadd2(acc[rr][2], u2h(wA1.x));
                acc[rr][3] = __hadd2(acc[rr][3], u2h(wA1.y));
                acc[rr][4] = __hadd2(acc[rr][4], u2h(wA2.x));
                acc[rr][5] = __hadd2(acc[rr][5], u2h(wA2.y));
            }
        }
        #pragma unroll
        for (int rr = 0; rr < ROWS; ++rr) {
            if (mB & (1 << rr)) {
                acc[rr][0] = __hadd2(acc[rr][0], u2h(wB0.x));
                acc[rr][1] = __hadd2(acc[rr][1], u2h(wB0.y));
                acc[rr][2] = __hadd2(acc[rr][2], u2h(wB1.x));
                acc[rr][3] = __hadd2(acc[rr][3], u2h(wB1.y));
                acc[rr][4] = __hadd2(acc[rr][4], u2h(wB2.x));
                acc[rr][5] = __hadd2(acc[rr][5], u2h(wB2.y));
            }
        }
    }
    for (; k < U; k += NSLOT) {
        if (k + ks < U) {                            // wave-uniform
            const int pkA = __builtin_amdgcn_readfirstlane(ulist[k + ks]);
            const int jA = pkA & 0x1FFF, mA = pkA >> 13;
            const char* rA = base + jA * 1536 + b0;
            const uint2 wA0 = *(const uint2*)(rA);
            const uint2 wA1 = *(const uint2*)(rA + 8);
            const uint2 wA2 = *(const uint2*)(rA + 16);
            #pragma unroll
            for (int rr = 0; rr < ROWS; ++rr) {
                if (mA & (1 << rr)) {
                    acc[rr][0] = __hadd2(acc[rr][0], u2h(wA0.x));
                    acc[rr][1] = __hadd2(acc[rr][1], u2h(wA0.y));
                    acc[rr][2] = __hadd2(acc[rr][2], u2h(wA1.x));
                    acc[rr][3] = __hadd2(acc[rr][3], u2h(wA1.y));
                    acc[rr][4] = __hadd2(acc[rr][4], u2h(wA2.x));
                    acc[rr][5] = __hadd2(acc[rr][5], u2h(wA2.y));
                }
            }
        }
    }

    // fold + norm + write, one row at a time through the shared partl buffer
    for (int rr = 0; rr < ROWS; ++rr) {
        partl[ks][cg][0] = make_uint2(h2u(acc[rr][0]), h2u(acc[rr][1]));
        partl[ks][cg][1] = make_uint2(h2u(acc[rr][2]), h2u(acc[rr][3]));
        partl[ks][cg][2] = make_uint2(h2u(acc[rr][4]), h2u(acc[rr][5]));
        __syncthreads();

        float re = 0.f, im = 0.f;
        if (t < DDIM) {
            const int sc = t / 6, comp = t % 6;
            #pragma unroll
            for (int s = 0; s < NSLOT; ++s) {
                const uint2 ww = partl[s][sc][comp >> 1];
                const float2 f = __half22float2(u2h((comp & 1) ? ww.y : ww.x));
                re += f.x; im += f.y;
            }
        }

        float p = fmaf(re, re, im * im);
        #pragma unroll
        for (int off = 32; off > 0; off >>= 1) p += __shfl_down(p, off, 64);
        if ((t & 63) == 0) red[t >> 6] = p;
        __syncthreads();
        const float tot = ((red[0] + red[1]) + (red[2] + red[3]))
                        + ((red[4] + red[5]) + (red[6] + red[7]));
        const float scale = 19.59591794226543f / sqrtf(tot);   // sqrt(384)/nrm

        if (t < DDIM) {
            const float2 ci = __half22float2(csS[(r0 + rr) * DDIM + t]);
            const float  Gr = fmaf(re, ci.x, im * ci.y);
            out[perm[r0 + rr] * DDIM + t] = Gr * scale;
        }
        __syncthreads();   // protect partl/red before next row's overwrite
    }
}

extern "C" void kernel_launch(void* const* d_in, const int* in_sizes, int n_in,
                              void* d_out, int out_size, void* d_ws, size_t ws_size,
                              hipStream_t stream)
{
    const float* pts = (const float*)d_in[0];
    const float* A   = (const float*)d_in[1];
    if (n_in >= 2 && in_sizes[0] == 3 * DDIM && in_sizes[1] == NPTS * 3) {
        pts = (const float*)d_in[1];
        A   = (const float*)d_in[0];
    }
    char* ws = (char*)d_ws;
    __half2* csS       = (__half2*)(ws + 0);
    float2*  xyS       = (float2*)(ws + 12582912);
    int*     perm      = (int*)(ws + 12648448);
    int*     cellStart = (int*)(ws + 12681216);
    float*   out       = (float*)d_out;

    setup_kernel<<<1, 1024, 0, stream>>>(pts, cellStart, perm, xyS);
    cs_kernel<<<NPTS, DDIM, 0, stream>>>(pts, A, perm, csS);
    row_kernel<<<NBLK, NTHR, 0, stream>>>(csS, xyS, perm, cellStart, out);
}